// Round 5
// baseline (449.901 us; speedup 1.0000x reference)
//
#include <hip/hip_runtime.h>
#include <math.h>

#define HP 265
#define NPIX 70225        // 265*265
#define ROWF 8480         // HP*32 elements per (b,h) row, channels-last
#define TWO_PI 6.28318530717958647692f

// ws layout (float offsets); xb is bf16 (ushort)
#define OFF_X     0            // [8][265][265][32] ushort  = 8,988,800 f32-slots
#define OFF_UPART 8988800      // [8][4][13][8480] cplx f32 = 7,055,360
#define OFF_G     16044160     // [2][8][32][24][12] cplx   =   294,912
#define OFF_A     16339072     // [8][265][32][24] f32      = 1,628,160
#define OFF_TF    17967232     // [265][13][2] f32          =     6,890
#define OFF_TS    17974124     // [272][32] ushort (16B-aligned)

typedef __attribute__((ext_vector_type(8))) short short8;
typedef __attribute__((ext_vector_type(4))) float f32x4;

__device__ __forceinline__ float gelu_f(float v){
  return 0.5f * v * (1.0f + erff(v * 0.70710678118654752f));
}
__device__ __forceinline__ unsigned short f2b(float f){
  unsigned u = __float_as_uint(f);
  u += 0x7FFFu + ((u >> 16) & 1u);
  return (unsigned short)(u >> 16);
}
__device__ __forceinline__ float b2f(unsigned short s){
  return __uint_as_float(((unsigned)s) << 16);
}
__device__ __forceinline__ unsigned pk(unsigned short lo, unsigned short hi){
  return (unsigned)lo | ((unsigned)hi << 16);
}

// Tf[h][k] = exp(-2pi i h k/265) f32; Tsyn[w][kap<24] = inverse-synth bf16 (invN folded)
__global__ void k_init(float* __restrict__ Tf, unsigned short* __restrict__ Ts){
  int idx = blockIdx.x*256 + threadIdx.x;
  if (idx < HP*13){
    int h = idx/13, k = idx%13;
    int t = (h*k) % HP;
    float s, c; sincosf(-TWO_PI*(float)t/(float)HP, &s, &c);
    Tf[2*idx] = c; Tf[2*idx+1] = s;
  }
  if (idx < 272*32){
    int w = idx >> 5, kap = idx & 31;
    unsigned short v = 0;
    if (w < HP && kap < 24){
      int k = kap >> 1;
      int t = (w*k) % HP;
      float s, c; sincosf(TWO_PI*(float)t/(float)HP, &s, &c);
      const float invN = 1.f/70225.f;
      float val = (!(kap&1)) ? invN*(k==0 ? 1.f : 2.f*c)
                             : ((k==0) ? 0.f : -invN*2.f*s);
      v = f2b(val);
    }
    Ts[idx] = v;
  }
}

// fc0 (3->32, bf16 channels-last, zero pad) + copy x_en/x_de to out
__global__ __launch_bounds__(256) void k_fc0(const float* __restrict__ xen,
                                             const float* __restrict__ w0,
                                             const float* __restrict__ b0,
                                             unsigned short* __restrict__ xb,
                                             float* __restrict__ out){
  int idx = blockIdx.x*256 + threadIdx.x;
  if (idx >= 8*NPIX) return;
  int w = idx % HP; int t = idx / HP; int h = t % HP; int b = t / HP;
  unsigned short o16[32];
  if (h < 256 && w < 256){
    const float* xp = xen + (((size_t)b*3)*256 + h)*256 + w;
    float c0 = xp[0], c1 = xp[65536], c2 = xp[131072];
    #pragma unroll
    for (int d = 0; d < 32; ++d)
      o16[d] = f2b(b0[d] + c0*w0[d] + c1*w0[32+d] + c2*w0[64+d]);
    size_t be = ((size_t)b*3)*65536 + (h<<8) + w;
    out[1769472 + be]          = c0;
    out[1769472 + be + 65536]  = c1;
    out[1769472 + be + 131072] = c2;
    if (((h|w)&3) == 0){
      size_t db = ((size_t)b*3)*4096 + ((h>>2)<<6) + (w>>2);
      out[98304 + db]        = c0;
      out[98304 + db + 4096] = c1;
      out[98304 + db + 8192] = c2;
    }
  } else {
    #pragma unroll
    for (int d = 0; d < 32; ++d) o16[d] = 0;
  }
  uint4* dst = (uint4*)(xb + (size_t)idx*32);
  #pragma unroll
  for (int q = 0; q < 4; ++q)
    dst[q] = make_uint4(pk(o16[8*q],o16[8*q+1]), pk(o16[8*q+2],o16[8*q+3]),
                        pk(o16[8*q+4],o16[8*q+5]), pk(o16[8*q+6],o16[8*q+7]));
}

// Row DFT over h, 13 modes, bf16 input, 2 elements/thread
__global__ __launch_bounds__(256) void k_dft_h(const unsigned short* __restrict__ xb,
                                               const float* __restrict__ Tf,
                                               float2* __restrict__ Upart){
  int t2 = blockIdx.x*256 + threadIdx.x;   // 0..4239
  if (t2 >= 4240) return;
  int hq = blockIdx.y, b = blockIdx.z;
  int h0 = hq*67;
  int h1 = (h0 + 67 < HP) ? h0 + 67 : HP;
  float ur0[13], ui0[13], ur1[13], ui1[13];
  #pragma unroll
  for (int k = 0; k < 13; ++k){ ur0[k]=0.f; ui0[k]=0.f; ur1[k]=0.f; ui1[k]=0.f; }
  const unsigned short* xp = xb + (size_t)(b*HP + h0)*ROWF + 2*t2;
  for (int h = h0; h < h1; ++h, xp += ROWF){
    unsigned u = *(const unsigned*)xp;
    float v0 = b2f((unsigned short)(u & 0xFFFF));
    float v1 = b2f((unsigned short)(u >> 16));
    const float* tw = Tf + h*26;          // uniform -> scalar loads
    #pragma unroll
    for (int k = 0; k < 13; ++k){
      float cr = tw[2*k], ci = tw[2*k+1];
      ur0[k] = fmaf(v0, cr, ur0[k]); ui0[k] = fmaf(v0, ci, ui0[k]);
      ur1[k] = fmaf(v1, cr, ur1[k]); ui1[k] = fmaf(v1, ci, ui1[k]);
    }
  }
  float* up = (float*)(Upart + ((size_t)(b*4 + hq))*13*ROWF + 2*t2);
  #pragma unroll
  for (int k = 0; k < 13; ++k)
    *(float4*)(up + (size_t)k*ROWF*2) = make_float4(ur0[k], ui0[k], ur1[k], ui1[k]);
}

// Column DFT + mode mix, one block per (j, b, ws). ws splits the w-sweep in 2;
// each block emits a partial G (mode mix is linear in X); k_idft_h sums them.
__global__ __launch_bounds__(256) void k_spec(const float2* __restrict__ Upart,
                                              const float* __restrict__ w1r,
                                              const float* __restrict__ w1i,
                                              const float* __restrict__ w2r,
                                              const float* __restrict__ w2i,
                                              float2* __restrict__ G, int l){
  __shared__ float part[256*25];
  __shared__ float Xs[32*25];
  int j = blockIdx.x;
  int b = blockIdx.y;
  int ws = blockIdx.z;
  int tid = threadIdx.x;
  int wsub = tid >> 5, i = tid & 31;
  int kk   = (j < 12) ? j : (24 - j);
  bool cj  = (j >= 12);
  float xr[12], xi[12];
  #pragma unroll
  for (int k = 0; k < 12; ++k){ xr[k] = 0.f; xi[k] = 0.f; }
  const float2* ub = Upart + ((size_t)(b*4*13 + kk))*ROWF;
  for (int w = ws*8 + wsub; w < HP; w += 16){
    const float2* p = ub + (size_t)w*32 + i;
    float2 u0 = p[0];
    float2 u1 = p[(size_t)13*ROWF];
    float2 u2 = p[(size_t)26*ROWF];
    float2 u3 = p[(size_t)39*ROWF];
    float ux = u0.x+u1.x+u2.x+u3.x;
    float uy = u0.y+u1.y+u2.y+u3.y;
    if (cj) uy = -uy;
    float bs, bc; sincosf(-TWO_PI*(float)w/(float)HP, &bs, &bc);
    float pr = 1.f, pi = 0.f;
    #pragma unroll
    for (int k = 0; k < 12; ++k){
      xr[k] = fmaf(ux, pr, fmaf(-uy, pi, xr[k]));
      xi[k] = fmaf(ux, pi, fmaf( uy, pr, xi[k]));
      float npr = pr*bc - pi*bs;
      pi = fmaf(pr, bs, pi*bc);
      pr = npr;
    }
  }
  #pragma unroll
  for (int k = 0; k < 12; ++k){
    part[tid*25 + 2*k]     = xr[k];
    part[tid*25 + 2*k + 1] = xi[k];
  }
  __syncthreads();
  {
    int sg = tid >> 5;
    int ii = tid & 31;
    #pragma unroll
    for (int s0 = 0; s0 < 3; ++s0){
      int s = sg*3 + s0;
      float acc = 0.f;
      #pragma unroll
      for (int wq = 0; wq < 8; ++wq) acc += part[(wq*32 + ii)*25 + s];
      Xs[ii*25 + s] = acc;
    }
  }
  __syncthreads();
  int ky = (j < 12) ? j : (j - 12);
  const float* wr = (j < 12) ? w1r : w2r;
  const float* wi = (j < 12) ? w1i : w2i;
  float2* Gp = G + (size_t)ws*73728;
  for (int p = tid; p < 384; p += 256){
    int o = p / 12, kx = p % 12;
    size_t wbase = (size_t)l*147456 + (size_t)o*144 + (size_t)ky*12 + kx;
    float gr = 0.f, gi = 0.f;
    #pragma unroll 4
    for (int i2 = 0; i2 < 32; ++i2){
      float xvr = Xs[i2*25 + 2*kx];
      float xvi = Xs[i2*25 + 2*kx + 1];
      float a = wr[wbase + (size_t)i2*4608];
      float c = wi[wbase + (size_t)i2*4608];
      gr += xvr*a - xvi*c;
      gi += xvr*c + xvi*a;
    }
    Gp[((size_t)(b*32 + o)*24 + j)*12 + kx] = make_float2(gr, gi);
  }
}

// Inverse row synthesis (sums the 2 G partials): A[b,h][o][2k]=Re, [2k+1]=Im
__global__ __launch_bounds__(320) void k_idft_h(const float2* __restrict__ G,
                                                float* __restrict__ A){
  __shared__ float2 gs[288];
  int bo = blockIdx.x;
  for (int i = threadIdx.x; i < 288; i += 320){
    float2 g0 = G[(size_t)bo*288 + i];
    float2 g1 = G[73728 + (size_t)bo*288 + i];
    gs[i] = make_float2(g0.x + g1.x, g0.y + g1.y);
  }
  __syncthreads();
  int h = threadIdx.x;
  if (h >= HP) return;
  float ar[12], ai[12];
  #pragma unroll
  for (int k = 0; k < 12; ++k){ ar[k] = 0.f; ai[k] = 0.f; }
  for (int j = 0; j < 24; ++j){
    int ky = (j < 12) ? j : (241 + j);
    int t = (ky*h) % HP;
    float s, c; sincosf(TWO_PI*(float)t/(float)HP, &s, &c);
    #pragma unroll
    for (int k = 0; k < 12; ++k){
      float2 g = gs[j*12 + k];
      ar[k] = fmaf(g.x, c, fmaf(-g.y, s, ar[k]));
      ai[k] = fmaf(g.x, s, fmaf( g.y, c, ai[k]));
    }
  }
  int b = bo >> 5, o = bo & 31;
  float4* ap = (float4*)(A + (((size_t)(b*HP + h))*32 + o)*24);
  #pragma unroll
  for (int k = 0; k < 6; ++k)
    ap[k] = make_float4(ar[2*k], ai[2*k], ar[2*k+1], ai[2*k+1]);
}

// MFMA final, 4 h-rows per block: C[w][o] = Tsyn@A + x@pw^T + bias; gelu (l<3).
// 68 tiles over 4 waves = 17 full rounds, no idle wave.
__global__ __launch_bounds__(256) void k_final(const float* __restrict__ A,
                                               const unsigned short* __restrict__ Tsyn,
                                               const float* __restrict__ pw_w,
                                               const float* __restrict__ pw_b,
                                               unsigned short* __restrict__ xb, int l){
  __shared__ unsigned short btA[4*32*40];
  __shared__ unsigned short btP[32*40];
  __shared__ float pwbs[32];
  __shared__ float buf[4][16*36];
  int tid = threadIdx.x;
  int h0 = blockIdx.x*4, b = blockIdx.y;
  for (int i = tid; i < 3072; i += 256){
    int hh = i/768, r = i - hh*768;
    int o = r/24, k = r - o*24;
    int h = h0 + hh;
    btA[hh*1280 + o*40 + k] = (h < HP) ? f2b(A[(size_t)(b*HP + h)*768 + r]) : 0;
  }
  for (int i = tid; i < 1024; i += 256){
    int hh = i >> 8, o = (i >> 3) & 31, c = 24 + (i & 7);
    btA[hh*1280 + o*40 + c] = 0;
  }
  for (int i = tid; i < 1024; i += 256)
    btP[(i>>5)*40 + (i&31)] = f2b(pw_w[l*1024 + i]);
  if (tid < 32) pwbs[tid] = pw_b[l*32 + tid];
  __syncthreads();
  int wid = tid>>6, lane = tid&63, lr = lane&15, g = lane>>4, lk = g*8;
  short8 bP0 = *(const short8*)&btP[lr*40 + lk];
  short8 bP1 = *(const short8*)&btP[(16+lr)*40 + lk];
  float bias0 = pwbs[lr], bias1 = pwbs[16+lr];
  float* bw = buf[wid];
  const f32x4 z4 = {0.f,0.f,0.f,0.f};
  for (int m = 0; m < 17; ++m){
    int tt = wid + 4*m;              // 0..67
    int hh = tt/17, wt = tt - hh*17;
    int h = h0 + hh;
    if (h >= HP) continue;
    int w0 = wt*16;
    unsigned short* xrow = xb + (size_t)(b*HP + h)*ROWF;
    short8 aT = *(const short8*)&Tsyn[(w0+lr)*32 + lk];
    short8 aX = *(const short8*)&xrow[(size_t)(w0+lr)*32 + lk];
    short8 bA0 = *(const short8*)&btA[hh*1280 + lr*40 + lk];
    short8 bA1 = *(const short8*)&btA[hh*1280 + (16+lr)*40 + lk];
    f32x4 a0 = __builtin_amdgcn_mfma_f32_16x16x32_bf16(aT, bA0, z4, 0,0,0);
    a0 = __builtin_amdgcn_mfma_f32_16x16x32_bf16(aX, bP0, a0, 0,0,0);
    f32x4 a1 = __builtin_amdgcn_mfma_f32_16x16x32_bf16(aT, bA1, z4, 0,0,0);
    a1 = __builtin_amdgcn_mfma_f32_16x16x32_bf16(aX, bP1, a1, 0,0,0);
    #pragma unroll
    for (int r = 0; r < 4; ++r){
      bw[(g*4+r)*36 + lr]      = a0[r] + bias0;
      bw[(g*4+r)*36 + 16 + lr] = a1[r] + bias1;
    }
    asm volatile("s_waitcnt lgkmcnt(0)" ::: "memory");
    __builtin_amdgcn_sched_barrier(0);
    int row = lane >> 2, c0 = (lane & 3)*8;
    int w = w0 + row;
    f32x4 v0 = *(const f32x4*)&bw[row*36 + c0];
    f32x4 v1 = *(const f32x4*)&bw[row*36 + c0 + 4];
    if (w < HP){
      unsigned short o8[8];
      #pragma unroll
      for (int q = 0; q < 4; ++q){
        float va = v0[q], vb = v1[q];
        if (l < 3){ va = gelu_f(va); vb = gelu_f(vb); }
        o8[q] = f2b(va); o8[4+q] = f2b(vb);
      }
      uint4* dst = (uint4*)&xrow[(size_t)w*32 + c0];
      *dst = make_uint4(pk(o8[0],o8[1]), pk(o8[2],o8[3]),
                        pk(o8[4],o8[5]), pk(o8[6],o8[7]));
    }
  }
}

// MFMA head: fc1 via MFMA; gelu + fc2(128->3) in-register with shfl_xor reduce
__global__ __launch_bounds__(256) void k_head(const unsigned short* __restrict__ xb,
                                              const float* __restrict__ xen,
                                              const float* __restrict__ fc1w,
                                              const float* __restrict__ fc1b,
                                              const float* __restrict__ fc2w,
                                              const float* __restrict__ fc2b,
                                              float* __restrict__ out){
  __shared__ unsigned short bt1[128*40];
  __shared__ float dl[4][64*4];
  int tid = threadIdx.x;
  int b = blockIdx.x >> 8, h = blockIdx.x & 255;
  for (int i = tid; i < 4096; i += 256){
    int k = i >> 7, n = i & 127;
    bt1[n*40 + k] = f2b(fc1w[i]);
  }
  __syncthreads();
  int wid = tid>>6, lane = tid&63, lr = lane&15, g = lane>>4, lk = g*8;
  short8 bf1[8];
  float b1l[8], w2l[8][3];
  #pragma unroll
  for (int nt = 0; nt < 8; ++nt){
    bf1[nt] = *(const short8*)&bt1[(nt*16+lr)*40 + lk];
    int n = nt*16 + lr;
    b1l[nt] = fc1b[n];
    w2l[nt][0] = fc2w[n*3+0];
    w2l[nt][1] = fc2w[n*3+1];
    w2l[nt][2] = fc2w[n*3+2];
  }
  float f2c0 = fc2b[0], f2c1 = fc2b[1], f2c2 = fc2b[2];
  const unsigned short* xrow = xb + (size_t)(b*HP + h)*ROWF;
  float* dlw = dl[wid];
  const f32x4 z4 = {0.f,0.f,0.f,0.f};
  #pragma unroll
  for (int m = 0; m < 4; ++m){
    int p0 = (wid*4 + m)*16;
    short8 ax = *(const short8*)&xrow[(size_t)(p0 + lr)*32 + lk];
    f32x4 acc[8];
    #pragma unroll
    for (int nt = 0; nt < 8; ++nt)
      acc[nt] = __builtin_amdgcn_mfma_f32_16x16x32_bf16(ax, bf1[nt], z4, 0,0,0);
    float sc[4][3];
    #pragma unroll
    for (int r = 0; r < 4; ++r){ sc[r][0]=0.f; sc[r][1]=0.f; sc[r][2]=0.f; }
    #pragma unroll
    for (int nt = 0; nt < 8; ++nt){
      #pragma unroll
      for (int r = 0; r < 4; ++r){
        float hv = gelu_f(acc[nt][r] + b1l[nt]);
        sc[r][0] = fmaf(hv, w2l[nt][0], sc[r][0]);
        sc[r][1] = fmaf(hv, w2l[nt][1], sc[r][1]);
        sc[r][2] = fmaf(hv, w2l[nt][2], sc[r][2]);
      }
    }
    #pragma unroll
    for (int off = 1; off <= 8; off <<= 1){
      #pragma unroll
      for (int r = 0; r < 4; ++r){
        sc[r][0] += __shfl_xor(sc[r][0], off);
        sc[r][1] += __shfl_xor(sc[r][1], off);
        sc[r][2] += __shfl_xor(sc[r][2], off);
      }
    }
    if (lr == 0){
      #pragma unroll
      for (int r = 0; r < 4; ++r){
        int px = m*16 + g*4 + r;
        dlw[px*4+0] = sc[r][0];
        dlw[px*4+1] = sc[r][1];
        dlw[px*4+2] = sc[r][2];
      }
    }
  }
  asm volatile("s_waitcnt lgkmcnt(0)" ::: "memory");
  __builtin_amdgcn_sched_barrier(0);
  int w = wid*64 + lane;
  float d0 = dlw[lane*4+0] + f2c0;
  float d1 = dlw[lane*4+1] + f2c1;
  float d2 = dlw[lane*4+2] + f2c2;
  size_t be = ((size_t)b*3)*65536 + (h<<8) + w;
  float p0 = d0 + xen[be];
  float p1 = d1 + xen[be + 65536];
  float p2 = d2 + xen[be + 131072];
  out[196608 + be]          = p0;
  out[196608 + be + 65536]  = p1;
  out[196608 + be + 131072] = p2;
  if (((h|w)&3) == 0){
    size_t db = ((size_t)b*3)*4096 + ((h>>2)<<6) + (w>>2);
    out[db]        = p0;
    out[db + 4096] = p1;
    out[db + 8192] = p2;
  }
}

extern "C" void kernel_launch(void* const* d_in, const int* in_sizes, int n_in,
                              void* d_out, int out_size, void* d_ws, size_t ws_size,
                              hipStream_t stream){
  const float* x_en  = (const float*)d_in[0];
  const float* fc0_w = (const float*)d_in[2];
  const float* fc0_b = (const float*)d_in[3];
  const float* w1r   = (const float*)d_in[4];
  const float* w1i   = (const float*)d_in[5];
  const float* w2r   = (const float*)d_in[6];
  const float* w2i   = (const float*)d_in[7];
  const float* pw_w  = (const float*)d_in[8];
  const float* pw_b  = (const float*)d_in[9];
  const float* fc1_w = (const float*)d_in[10];
  const float* fc1_b = (const float*)d_in[11];
  const float* fc2_w = (const float*)d_in[12];
  const float* fc2_b = (const float*)d_in[13];
  float* out = (float*)d_out;
  float* ws  = (float*)d_ws;

  unsigned short* xb = (unsigned short*)(ws + OFF_X);
  float2* Upart = (float2*)(ws + OFF_UPART);
  float2* G     = (float2*)(ws + OFF_G);
  float*  A     = ws + OFF_A;
  float*  Tf    = ws + OFF_TF;
  unsigned short* Ts = (unsigned short*)(ws + OFF_TS);

  k_init<<<34, 256, 0, stream>>>(Tf, Ts);
  k_fc0<<<2195, 256, 0, stream>>>(x_en, fc0_w, fc0_b, xb, out);
  for (int l = 0; l < 4; ++l){
    k_dft_h<<<dim3(17,4,8), 256, 0, stream>>>(xb, Tf, Upart);
    k_spec<<<dim3(24,8,2), 256, 0, stream>>>(Upart, w1r, w1i, w2r, w2i, G, l);
    k_idft_h<<<256, 320, 0, stream>>>(G, A);
    k_final<<<dim3(67,8), 256, 0, stream>>>(A, Ts, pw_w, pw_b, xb, l);
  }
  k_head<<<2048, 256, 0, stream>>>(xb, x_en, fc1_w, fc1_b, fc2_w, fc2_b, out);
}

// Round 6
// 413.475 us; speedup vs baseline: 1.0881x; 1.0881x over previous
//
#include <hip/hip_runtime.h>
#include <math.h>

#define HP 265
#define NPIX 70225        // 265*265
#define ROWF 8480         // HP*32 elements per (b,h) row, channels-last
#define TWO_PI 6.28318530717958647692f

// ws layout (float offsets); xb/A16/weights are bf16 (ushort)
#define OFF_X     0            // [8][265][265][32] ushort  = 8,988,800 slots
#define OFF_UPART 8988800      // [8][4][13][8480] cplx f32 = 7,055,360
#define OFF_G     16044160     // [2][8][32][24][12] cplx   =   294,912
#define OFF_A     16339072     // [8][265][32][32] ushort   = 1,085,440 slots
#define OFF_TF    17424512     // [265][13][2] f32          =     6,890
#define OFF_TS    17431404     // [272][32] ushort          =     4,352 slots
#define OFF_W1B   17435756     // [128][32] ushort          =     2,048 slots
#define OFF_W2B   17437804     // [16][128] ushort          =     1,024 slots
#define OFF_PWB   17438828     // [4][32][32] ushort        =     2,048 slots

typedef __attribute__((ext_vector_type(8))) short short8;
typedef __attribute__((ext_vector_type(4))) float f32x4;

__device__ __forceinline__ float gelu_f(float v){
  return 0.5f * v * (1.0f + erff(v * 0.70710678118654752f));
}
__device__ __forceinline__ unsigned short f2b(float f){
  unsigned u = __float_as_uint(f);
  u += 0x7FFFu + ((u >> 16) & 1u);
  return (unsigned short)(u >> 16);
}
__device__ __forceinline__ float b2f(unsigned short s){
  return __uint_as_float(((unsigned)s) << 16);
}
__device__ __forceinline__ unsigned pk(unsigned short lo, unsigned short hi){
  return (unsigned)lo | ((unsigned)hi << 16);
}

// Twiddles + bf16 weight pre-conversion (runs once per call; tiny)
__global__ void k_init(float* __restrict__ Tf, unsigned short* __restrict__ Ts,
                       unsigned short* __restrict__ w1b, unsigned short* __restrict__ w2b,
                       unsigned short* __restrict__ pwb,
                       const float* __restrict__ fc1w, const float* __restrict__ fc2w,
                       const float* __restrict__ pw_w){
  int idx = blockIdx.x*256 + threadIdx.x;
  if (idx < HP*13){
    int h = idx/13, k = idx%13;
    int t = (h*k) % HP;
    float s, c; sincosf(-TWO_PI*(float)t/(float)HP, &s, &c);
    Tf[2*idx] = c; Tf[2*idx+1] = s;
  }
  if (idx < 272*32){
    int w = idx >> 5, kap = idx & 31;
    unsigned short v = 0;
    if (w < HP && kap < 24){
      int k = kap >> 1;
      int t = (w*k) % HP;
      float s, c; sincosf(TWO_PI*(float)t/(float)HP, &s, &c);
      const float invN = 1.f/70225.f;
      float val = (!(kap&1)) ? invN*(k==0 ? 1.f : 2.f*c)
                             : ((k==0) ? 0.f : -invN*2.f*s);
      v = f2b(val);
    }
    Ts[idx] = v;
  }
  if (idx < 4096){                      // w1b[n*32+k] = fc1w[k*128+n]
    int n = idx >> 5, k = idx & 31;
    w1b[idx] = f2b(fc1w[k*128 + n]);
  }
  if (idx < 2048){                      // w2b[n*128+k] = fc2w[k*3+n], n<3 else 0
    int n = idx >> 7, k = idx & 127;
    w2b[idx] = (n < 3) ? f2b(fc2w[k*3 + n]) : (unsigned short)0;
  }
  if (idx < 4096)                       // pwb = pw_w (same [l][o][i] layout)
    pwb[idx] = f2b(pw_w[idx]);
}

// fc0 (3->32, bf16 channels-last, zero pad) + copy x_en/x_de to out
__global__ __launch_bounds__(256) void k_fc0(const float* __restrict__ xen,
                                             const float* __restrict__ w0,
                                             const float* __restrict__ b0,
                                             unsigned short* __restrict__ xb,
                                             float* __restrict__ out){
  int idx = blockIdx.x*256 + threadIdx.x;
  if (idx >= 8*NPIX) return;
  int w = idx % HP; int t = idx / HP; int h = t % HP; int b = t / HP;
  unsigned short o16[32];
  if (h < 256 && w < 256){
    const float* xp = xen + (((size_t)b*3)*256 + h)*256 + w;
    float c0 = xp[0], c1 = xp[65536], c2 = xp[131072];
    #pragma unroll
    for (int d = 0; d < 32; ++d)
      o16[d] = f2b(b0[d] + c0*w0[d] + c1*w0[32+d] + c2*w0[64+d]);
    size_t be = ((size_t)b*3)*65536 + (h<<8) + w;
    out[1769472 + be]          = c0;
    out[1769472 + be + 65536]  = c1;
    out[1769472 + be + 131072] = c2;
    if (((h|w)&3) == 0){
      size_t db = ((size_t)b*3)*4096 + ((h>>2)<<6) + (w>>2);
      out[98304 + db]        = c0;
      out[98304 + db + 4096] = c1;
      out[98304 + db + 8192] = c2;
    }
  } else {
    #pragma unroll
    for (int d = 0; d < 32; ++d) o16[d] = 0;
  }
  uint4* dst = (uint4*)(xb + (size_t)idx*32);
  #pragma unroll
  for (int q = 0; q < 4; ++q)
    dst[q] = make_uint4(pk(o16[8*q],o16[8*q+1]), pk(o16[8*q+2],o16[8*q+3]),
                        pk(o16[8*q+4],o16[8*q+5]), pk(o16[8*q+6],o16[8*q+7]));
}

// Row DFT over h, 13 modes, bf16 input, 2 elements/thread
__global__ __launch_bounds__(256) void k_dft_h(const unsigned short* __restrict__ xb,
                                               const float* __restrict__ Tf,
                                               float2* __restrict__ Upart){
  int t2 = blockIdx.x*256 + threadIdx.x;   // 0..4239
  if (t2 >= 4240) return;
  int hq = blockIdx.y, b = blockIdx.z;
  int h0 = hq*67;
  int h1 = (h0 + 67 < HP) ? h0 + 67 : HP;
  float ur0[13], ui0[13], ur1[13], ui1[13];
  #pragma unroll
  for (int k = 0; k < 13; ++k){ ur0[k]=0.f; ui0[k]=0.f; ur1[k]=0.f; ui1[k]=0.f; }
  const unsigned short* xp = xb + (size_t)(b*HP + h0)*ROWF + 2*t2;
  for (int h = h0; h < h1; ++h, xp += ROWF){
    unsigned u = *(const unsigned*)xp;
    float v0 = b2f((unsigned short)(u & 0xFFFF));
    float v1 = b2f((unsigned short)(u >> 16));
    const float* tw = Tf + h*26;          // uniform -> scalar loads
    #pragma unroll
    for (int k = 0; k < 13; ++k){
      float cr = tw[2*k], ci = tw[2*k+1];
      ur0[k] = fmaf(v0, cr, ur0[k]); ui0[k] = fmaf(v0, ci, ui0[k]);
      ur1[k] = fmaf(v1, cr, ur1[k]); ui1[k] = fmaf(v1, ci, ui1[k]);
    }
  }
  float* up = (float*)(Upart + ((size_t)(b*4 + hq))*13*ROWF + 2*t2);
  #pragma unroll
  for (int k = 0; k < 13; ++k)
    *(float4*)(up + (size_t)k*ROWF*2) = make_float4(ur0[k], ui0[k], ur1[k], ui1[k]);
}

// Column DFT + mode mix, one block per (j, b, ws); partial G per ws half
__global__ __launch_bounds__(256) void k_spec(const float2* __restrict__ Upart,
                                              const float* __restrict__ w1r,
                                              const float* __restrict__ w1i,
                                              const float* __restrict__ w2r,
                                              const float* __restrict__ w2i,
                                              float2* __restrict__ G, int l){
  __shared__ float part[256*25];
  __shared__ float Xs[32*25];
  int j = blockIdx.x;
  int b = blockIdx.y;
  int ws = blockIdx.z;
  int tid = threadIdx.x;
  int wsub = tid >> 5, i = tid & 31;
  int kk   = (j < 12) ? j : (24 - j);
  bool cj  = (j >= 12);
  float xr[12], xi[12];
  #pragma unroll
  for (int k = 0; k < 12; ++k){ xr[k] = 0.f; xi[k] = 0.f; }
  const float2* ub = Upart + ((size_t)(b*4*13 + kk))*ROWF;
  for (int w = ws*8 + wsub; w < HP; w += 16){
    const float2* p = ub + (size_t)w*32 + i;
    float2 u0 = p[0];
    float2 u1 = p[(size_t)13*ROWF];
    float2 u2 = p[(size_t)26*ROWF];
    float2 u3 = p[(size_t)39*ROWF];
    float ux = u0.x+u1.x+u2.x+u3.x;
    float uy = u0.y+u1.y+u2.y+u3.y;
    if (cj) uy = -uy;
    float bs, bc; sincosf(-TWO_PI*(float)w/(float)HP, &bs, &bc);
    float pr = 1.f, pi = 0.f;
    #pragma unroll
    for (int k = 0; k < 12; ++k){
      xr[k] = fmaf(ux, pr, fmaf(-uy, pi, xr[k]));
      xi[k] = fmaf(ux, pi, fmaf( uy, pr, xi[k]));
      float npr = pr*bc - pi*bs;
      pi = fmaf(pr, bs, pi*bc);
      pr = npr;
    }
  }
  #pragma unroll
  for (int k = 0; k < 12; ++k){
    part[tid*25 + 2*k]     = xr[k];
    part[tid*25 + 2*k + 1] = xi[k];
  }
  __syncthreads();
  {
    int sg = tid >> 5;
    int ii = tid & 31;
    #pragma unroll
    for (int s0 = 0; s0 < 3; ++s0){
      int s = sg*3 + s0;
      float acc = 0.f;
      #pragma unroll
      for (int wq = 0; wq < 8; ++wq) acc += part[(wq*32 + ii)*25 + s];
      Xs[ii*25 + s] = acc;
    }
  }
  __syncthreads();
  int ky = (j < 12) ? j : (j - 12);
  const float* wr = (j < 12) ? w1r : w2r;
  const float* wi = (j < 12) ? w1i : w2i;
  float2* Gp = G + (size_t)ws*73728;
  for (int p = tid; p < 384; p += 256){
    int o = p / 12, kx = p % 12;
    size_t wbase = (size_t)l*147456 + (size_t)o*144 + (size_t)ky*12 + kx;
    float gr = 0.f, gi = 0.f;
    #pragma unroll 4
    for (int i2 = 0; i2 < 32; ++i2){
      float xvr = Xs[i2*25 + 2*kx];
      float xvi = Xs[i2*25 + 2*kx + 1];
      float a = wr[wbase + (size_t)i2*4608];
      float c = wi[wbase + (size_t)i2*4608];
      gr += xvr*a - xvi*c;
      gi += xvr*c + xvi*a;
    }
    Gp[((size_t)(b*32 + o)*24 + j)*12 + kx] = make_float2(gr, gi);
  }
}

// Inverse row synthesis (sums the 2 G partials); writes A as bf16 [b][h][o][32]
// (kap 24..31 zero-padded = ready-to-load MFMA B-fragment rows)
__global__ __launch_bounds__(320) void k_idft_h(const float2* __restrict__ G,
                                                unsigned short* __restrict__ A16){
  __shared__ float2 gs[288];
  int bo = blockIdx.x;
  for (int i = threadIdx.x; i < 288; i += 320){
    float2 g0 = G[(size_t)bo*288 + i];
    float2 g1 = G[73728 + (size_t)bo*288 + i];
    gs[i] = make_float2(g0.x + g1.x, g0.y + g1.y);
  }
  __syncthreads();
  int h = threadIdx.x;
  if (h >= HP) return;
  float ar[12], ai[12];
  #pragma unroll
  for (int k = 0; k < 12; ++k){ ar[k] = 0.f; ai[k] = 0.f; }
  for (int j = 0; j < 24; ++j){
    int ky = (j < 12) ? j : (241 + j);
    int t = (ky*h) % HP;
    float s, c; sincosf(TWO_PI*(float)t/(float)HP, &s, &c);
    #pragma unroll
    for (int k = 0; k < 12; ++k){
      float2 g = gs[j*12 + k];
      ar[k] = fmaf(g.x, c, fmaf(-g.y, s, ar[k]));
      ai[k] = fmaf(g.x, s, fmaf( g.y, c, ai[k]));
    }
  }
  int b = bo >> 5, o = bo & 31;
  unsigned short o16[32];
  #pragma unroll
  for (int k = 0; k < 12; ++k){ o16[2*k] = f2b(ar[k]); o16[2*k+1] = f2b(ai[k]); }
  #pragma unroll
  for (int k = 24; k < 32; ++k) o16[k] = 0;
  uint4* ap = (uint4*)(A16 + (((size_t)(b*HP + h))*32 + o)*32);
  #pragma unroll
  for (int q = 0; q < 4; ++q)
    ap[q] = make_uint4(pk(o16[8*q],o16[8*q+1]), pk(o16[8*q+2],o16[8*q+3]),
                       pk(o16[8*q+4],o16[8*q+5]), pk(o16[8*q+6],o16[8*q+7]));
}

// MFMA final, 4 h-rows/block, zero LDS staging: all fragments straight from
// global (A16/Tsyn/pwb are bf16, L1/L2-hot). 68 tiles over 4 waves = 17 rounds.
__global__ __launch_bounds__(256) void k_final(const unsigned short* __restrict__ A16,
                                               const unsigned short* __restrict__ Tsyn,
                                               const unsigned short* __restrict__ pwb,
                                               const float* __restrict__ pw_b,
                                               unsigned short* __restrict__ xb, int l){
  __shared__ float buf[4][16*36];
  int tid = threadIdx.x;
  int h0 = blockIdx.x*4, b = blockIdx.y;
  int wid = tid>>6, lane = tid&63, lr = lane&15, g = lane>>4, lk = g*8;
  short8 bP0 = *(const short8*)&pwb[l*1024 + lr*32 + lk];
  short8 bP1 = *(const short8*)&pwb[l*1024 + (16+lr)*32 + lk];
  float bias0 = pw_b[l*32 + lr], bias1 = pw_b[l*32 + 16 + lr];
  float* bw = buf[wid];
  const f32x4 z4 = {0.f,0.f,0.f,0.f};
  for (int m = 0; m < 17; ++m){
    int tt = wid + 4*m;              // 0..67
    int hh = tt/17, wt = tt - hh*17;
    int h = h0 + hh;
    if (h >= HP) continue;
    int w0 = wt*16;
    unsigned short* xrow = xb + (size_t)(b*HP + h)*ROWF;
    const unsigned short* arow = A16 + (size_t)(b*HP + h)*1024;
    short8 aT  = *(const short8*)&Tsyn[(w0+lr)*32 + lk];
    short8 aX  = *(const short8*)&xrow[(size_t)(w0+lr)*32 + lk];
    short8 bA0 = *(const short8*)&arow[lr*32 + lk];
    short8 bA1 = *(const short8*)&arow[(16+lr)*32 + lk];
    f32x4 a0 = __builtin_amdgcn_mfma_f32_16x16x32_bf16(aT, bA0, z4, 0,0,0);
    a0 = __builtin_amdgcn_mfma_f32_16x16x32_bf16(aX, bP0, a0, 0,0,0);
    f32x4 a1 = __builtin_amdgcn_mfma_f32_16x16x32_bf16(aT, bA1, z4, 0,0,0);
    a1 = __builtin_amdgcn_mfma_f32_16x16x32_bf16(aX, bP1, a1, 0,0,0);
    #pragma unroll
    for (int r = 0; r < 4; ++r){
      bw[(g*4+r)*36 + lr]      = a0[r] + bias0;
      bw[(g*4+r)*36 + 16 + lr] = a1[r] + bias1;
    }
    asm volatile("s_waitcnt lgkmcnt(0)" ::: "memory");
    __builtin_amdgcn_sched_barrier(0);
    int row = lane >> 2, c0 = (lane & 3)*8;
    int w = w0 + row;
    f32x4 v0 = *(const f32x4*)&bw[row*36 + c0];
    f32x4 v1 = *(const f32x4*)&bw[row*36 + c0 + 4];
    if (w < HP){
      unsigned short o8[8];
      #pragma unroll
      for (int q = 0; q < 4; ++q){
        float va = v0[q], vb = v1[q];
        if (l < 3){ va = gelu_f(va); vb = gelu_f(vb); }
        o8[q] = f2b(va); o8[4+q] = f2b(vb);
      }
      uint4* dst = (uint4*)&xrow[(size_t)w*32 + c0];
      *dst = make_uint4(pk(o8[0],o8[1]), pk(o8[2],o8[3]),
                        pk(o8[4],o8[5]), pk(o8[6],o8[7]));
    }
  }
}

// MFMA head: fc1 via MFMA (fragments from global bf16), gelu -> LDS P (bf16)
// -> fc2 via MFMA, +x_en, write pred & pred_de. No block-wide syncs.
__global__ __launch_bounds__(256) void k_head(const unsigned short* __restrict__ xb,
                                              const float* __restrict__ xen,
                                              const unsigned short* __restrict__ w1b,
                                              const float* __restrict__ fc1b,
                                              const unsigned short* __restrict__ w2b,
                                              const float* __restrict__ fc2b,
                                              float* __restrict__ out){
  __shared__ unsigned short Pm[4][16*136];
  __shared__ float dl[4][64*4];
  int tid = threadIdx.x;
  int b = blockIdx.x >> 8, h = blockIdx.x & 255;
  int wid = tid>>6, lane = tid&63, lr = lane&15, g = lane>>4, lk = g*8;
  short8 bf1[8], bf2[4];
  float b1l[8];
  #pragma unroll
  for (int nt = 0; nt < 8; ++nt){
    int n = nt*16 + lr;
    bf1[nt] = *(const short8*)&w1b[n*32 + lk];
    b1l[nt] = fc1b[n];
  }
  #pragma unroll
  for (int ks = 0; ks < 4; ++ks)
    bf2[ks] = *(const short8*)&w2b[lr*128 + ks*32 + lk];
  float f2c0 = fc2b[0], f2c1 = fc2b[1], f2c2 = fc2b[2];
  const unsigned short* xrow = xb + (size_t)(b*HP + h)*ROWF;
  unsigned short* P = Pm[wid];
  float* dlw = dl[wid];
  const f32x4 z4 = {0.f,0.f,0.f,0.f};
  #pragma unroll
  for (int m = 0; m < 4; ++m){
    int p0 = (wid*4 + m)*16;
    short8 ax = *(const short8*)&xrow[(size_t)(p0 + lr)*32 + lk];
    f32x4 acc[8];
    #pragma unroll
    for (int nt = 0; nt < 8; ++nt)
      acc[nt] = __builtin_amdgcn_mfma_f32_16x16x32_bf16(ax, bf1[nt], z4, 0,0,0);
    #pragma unroll
    for (int nt = 0; nt < 8; ++nt){
      int n = nt*16 + lr;
      float bias = b1l[nt];
      #pragma unroll
      for (int r = 0; r < 4; ++r)
        P[(g*4 + r)*136 + n] = f2b(gelu_f(acc[nt][r] + bias));
    }
    asm volatile("s_waitcnt lgkmcnt(0)" ::: "memory");
    __builtin_amdgcn_sched_barrier(0);
    f32x4 a2 = z4;
    #pragma unroll
    for (int ks = 0; ks < 4; ++ks){
      short8 ap = *(const short8*)&P[lr*136 + ks*32 + lk];
      a2 = __builtin_amdgcn_mfma_f32_16x16x32_bf16(ap, bf2[ks], a2, 0,0,0);
    }
    if (lr < 3){
      #pragma unroll
      for (int r = 0; r < 4; ++r)
        dl[wid][(m*16 + g*4 + r)*4 + lr] = a2[r];
    }
  }
  asm volatile("s_waitcnt lgkmcnt(0)" ::: "memory");
  __builtin_amdgcn_sched_barrier(0);
  int w = wid*64 + lane;
  float d0 = dlw[lane*4+0] + f2c0;
  float d1 = dlw[lane*4+1] + f2c1;
  float d2 = dlw[lane*4+2] + f2c2;
  size_t be = ((size_t)b*3)*65536 + (h<<8) + w;
  float p0 = d0 + xen[be];
  float p1 = d1 + xen[be + 65536];
  float p2 = d2 + xen[be + 131072];
  out[196608 + be]          = p0;
  out[196608 + be + 65536]  = p1;
  out[196608 + be + 131072] = p2;
  if (((h|w)&3) == 0){
    size_t db = ((size_t)b*3)*4096 + ((h>>2)<<6) + (w>>2);
    out[db]        = p0;
    out[db + 4096] = p1;
    out[db + 8192] = p2;
  }
}

extern "C" void kernel_launch(void* const* d_in, const int* in_sizes, int n_in,
                              void* d_out, int out_size, void* d_ws, size_t ws_size,
                              hipStream_t stream){
  const float* x_en  = (const float*)d_in[0];
  const float* fc0_w = (const float*)d_in[2];
  const float* fc0_b = (const float*)d_in[3];
  const float* w1r   = (const float*)d_in[4];
  const float* w1i   = (const float*)d_in[5];
  const float* w2r   = (const float*)d_in[6];
  const float* w2i   = (const float*)d_in[7];
  const float* pw_w  = (const float*)d_in[8];
  const float* pw_b  = (const float*)d_in[9];
  const float* fc1_w = (const float*)d_in[10];
  const float* fc1_b = (const float*)d_in[11];
  const float* fc2_w = (const float*)d_in[12];
  const float* fc2_b = (const float*)d_in[13];
  float* out = (float*)d_out;
  float* ws  = (float*)d_ws;

  unsigned short* xb = (unsigned short*)(ws + OFF_X);
  float2* Upart = (float2*)(ws + OFF_UPART);
  float2* G     = (float2*)(ws + OFF_G);
  unsigned short* A16 = (unsigned short*)(ws + OFF_A);
  float*  Tf    = ws + OFF_TF;
  unsigned short* Ts  = (unsigned short*)(ws + OFF_TS);
  unsigned short* w1b = (unsigned short*)(ws + OFF_W1B);
  unsigned short* w2b = (unsigned short*)(ws + OFF_W2B);
  unsigned short* pwb = (unsigned short*)(ws + OFF_PWB);

  k_init<<<34, 256, 0, stream>>>(Tf, Ts, w1b, w2b, pwb, fc1_w, fc2_w, pw_w);
  k_fc0<<<2195, 256, 0, stream>>>(x_en, fc0_w, fc0_b, xb, out);
  for (int l = 0; l < 4; ++l){
    k_dft_h<<<dim3(17,4,8), 256, 0, stream>>>(xb, Tf, Upart);
    k_spec<<<dim3(24,8,2), 256, 0, stream>>>(Upart, w1r, w1i, w2r, w2i, G, l);
    k_idft_h<<<256, 320, 0, stream>>>(G, A16);
    k_final<<<dim3(67,8), 256, 0, stream>>>(A16, Ts, pwb, pw_b, xb, l);
  }
  k_head<<<2048, 256, 0, stream>>>(xb, x_en, w1b, fc1_b, w2b, fc2_b, out);
}

// Round 8
// 354.220 us; speedup vs baseline: 1.2701x; 1.1673x over previous
//
#include <hip/hip_runtime.h>
#include <math.h>

#define HP 265
#define NPIX 70225        // 265*265
#define ROWF 8480         // HP*32 elements per (b,h) row, channels-last
#define TWO_PI 6.28318530717958647692f

// ws layout (float offsets); xb/A16/weights/twiddle-mats are bf16 (ushort)
#define OFF_X     0            // [8][265][265][32] ushort  = 8,988,800 slots
#define OFF_U     8988800      // [8][26][8480] f32         = 1,763,840
#define OFF_G     10752640     // [2][8][32][24][12] cplx   =   294,912
#define OFF_A     11047552     // [8][265][32][32] ushort   = 1,085,440 slots
#define OFF_TFB   12132992     // [32][288] ushort          =     4,608 slots
#define OFF_TS    12137600     // [272][32] ushort          =     4,352 slots
#define OFF_W1B   12141952     // [128][32] ushort          =     2,048 slots
#define OFF_W2B   12144000     // [16][128] ushort          =     1,024 slots
#define OFF_PWB   12145024     // [4][32][32] ushort        =     2,048 slots

typedef __attribute__((ext_vector_type(8))) short short8;
typedef __attribute__((ext_vector_type(4))) float f32x4;

// fast exact-erf GELU (A&S 7.1.26, |err| < 1.6e-7)
__device__ __forceinline__ float gelu_f(float v){
  float x  = v * 0.70710678118654752f;
  float ax = fabsf(x);
  float t  = __builtin_amdgcn_rcpf(fmaf(0.3275911f, ax, 1.0f));
  float p  = fmaf(t, 1.061405429f, -1.453152027f);
  p = fmaf(t, p, 1.421413741f);
  p = fmaf(t, p, -0.284496736f);
  p = fmaf(t, p, 0.254829592f);
  p = p * t;
  float e = __expf(-ax*ax);
  float erfv = copysignf(fmaf(-p, e, 1.0f), x);
  return 0.5f * v * (1.0f + erfv);
}
__device__ __forceinline__ unsigned short f2b(float f){
  unsigned u = __float_as_uint(f);
  u += 0x7FFFu + ((u >> 16) & 1u);
  return (unsigned short)(u >> 16);
}
__device__ __forceinline__ float b2f(unsigned short s){
  return __uint_as_float(((unsigned)s) << 16);
}
__device__ __forceinline__ unsigned pk(unsigned short lo, unsigned short hi){
  return (unsigned)lo | ((unsigned)hi << 16);
}

// Twiddle mats + bf16 weight pre-conversion (tiny, once per call)
__global__ void k_init(unsigned short* __restrict__ Tfb, unsigned short* __restrict__ Ts,
                       unsigned short* __restrict__ w1b, unsigned short* __restrict__ w2b,
                       unsigned short* __restrict__ pwb,
                       const float* __restrict__ fc1w, const float* __restrict__ fc2w,
                       const float* __restrict__ pw_w){
  int idx = blockIdx.x*256 + threadIdx.x;
  if (idx < 32*288){                    // analysis twiddles: row 2k=cos, 2k+1=-sin
    int m = idx / 288, hc = idx % 288;
    unsigned short v = 0;
    if (m < 26 && hc < 265){
      int k = m >> 1;
      int t = (hc*k) % HP;
      float s, c; sincosf(TWO_PI*(float)t/(float)HP, &s, &c);
      v = f2b((m & 1) ? -s : c);
    }
    Tfb[idx] = v;
  }
  if (idx < 272*32){                    // synthesis twiddles (invN folded)
    int w = idx >> 5, kap = idx & 31;
    unsigned short v = 0;
    if (w < HP && kap < 24){
      int k = kap >> 1;
      int t = (w*k) % HP;
      float s, c; sincosf(TWO_PI*(float)t/(float)HP, &s, &c);
      const float invN = 1.f/70225.f;
      float val = (!(kap&1)) ? invN*(k==0 ? 1.f : 2.f*c)
                             : ((k==0) ? 0.f : -invN*2.f*s);
      v = f2b(val);
    }
    Ts[idx] = v;
  }
  if (idx < 4096){                      // w1b[n*32+k] = fc1w[k*128+n]
    int n = idx >> 5, k = idx & 31;
    w1b[idx] = f2b(fc1w[k*128 + n]);
  }
  if (idx < 2048){                      // w2b[n*128+k] = fc2w[k*3+n], n<3 else 0
    int n = idx >> 7, k = idx & 127;
    w2b[idx] = (n < 3) ? f2b(fc2w[k*3 + n]) : (unsigned short)0;
  }
  if (idx < 4096)                       // pwb = pw_w bf16 (same [l][o][i] layout)
    pwb[idx] = f2b(pw_w[idx]);
}

// fc0 (3->32, bf16 channels-last, zero pad) + copy x_en/x_de to out
__global__ __launch_bounds__(256) void k_fc0(const float* __restrict__ xen,
                                             const float* __restrict__ w0,
                                             const float* __restrict__ b0,
                                             unsigned short* __restrict__ xb,
                                             float* __restrict__ out){
  int idx = blockIdx.x*256 + threadIdx.x;
  if (idx >= 8*NPIX) return;
  int w = idx % HP; int t = idx / HP; int h = t % HP; int b = t / HP;
  unsigned short o16[32];
  if (h < 256 && w < 256){
    const float* xp = xen + (((size_t)b*3)*256 + h)*256 + w;
    float c0 = xp[0], c1 = xp[65536], c2 = xp[131072];
    #pragma unroll
    for (int d = 0; d < 32; ++d)
      o16[d] = f2b(b0[d] + c0*w0[d] + c1*w0[32+d] + c2*w0[64+d]);
    size_t be = ((size_t)b*3)*65536 + (h<<8) + w;
    out[1769472 + be]          = c0;
    out[1769472 + be + 65536]  = c1;
    out[1769472 + be + 131072] = c2;
    if (((h|w)&3) == 0){
      size_t db = ((size_t)b*3)*4096 + ((h>>2)<<6) + (w>>2);
      out[98304 + db]        = c0;
      out[98304 + db + 4096] = c1;
      out[98304 + db + 8192] = c2;
    }
  } else {
    #pragma unroll
    for (int d = 0; d < 32; ++d) o16[d] = 0;
  }
  uint4* dst = (uint4*)(xb + (size_t)idx*32);
  #pragma unroll
  for (int q = 0; q < 4; ++q)
    dst[q] = make_uint4(pk(o16[8*q],o16[8*q+1]), pk(o16[8*q+2],o16[8*q+3]),
                        pk(o16[8*q+4],o16[8*q+5]), pk(o16[8*q+6],o16[8*q+7]));
}

// MFMA h-DFT: U[b][m<26][n=8480] = sum_h Tfb[m][h] * x[b][h][n]
// M=32(pad 26), K=288(pad 265). B-side padding rows are ZEROED at staging
// (must not rely on A-zeros: 0*NaN = NaN through the K-reduction).
__global__ __launch_bounds__(256) void k_dftm(const unsigned short* __restrict__ xb,
                                              const unsigned short* __restrict__ Tfb,
                                              float* __restrict__ U32){
  __shared__ unsigned short xT[64*40];   // [n][k] transposed tile, 16B-aligned rows
  int n0 = blockIdx.x*64;
  int b  = blockIdx.y;
  int tid = threadIdx.x;
  int wv = tid>>6, lane = tid&63, lr = lane&15, g = lane>>4;
  int nn = tid & 63, hq8 = tid >> 6;     // staging role: column nn, h-group hq8
  int wch = hq8 ^ ((nn>>3)&3);           // swizzled k-chunk slot for writes
  f32x4 acc0 = {0.f,0.f,0.f,0.f}, acc1 = {0.f,0.f,0.f,0.f};
  int nl = wv*16 + lr;                   // n-within-tile for MFMA B-frag
  int rch = g ^ ((nl>>3)&3);             // matching swizzle on reads
  for (int kc = 0; kc < 9; ++kc){
    __syncthreads();
    short8 hv;
    int hbase = kc*32 + hq8*8;
    #pragma unroll
    for (int q = 0; q < 8; ++q){
      int h = hbase + q;
      hv[q] = (h < HP) ? (short)xb[(size_t)(b*HP + h)*ROWF + n0 + nn] : (short)0;
    }
    *(short8*)&xT[nn*40 + wch*8] = hv;
    __syncthreads();
    short8 bX  = *(const short8*)&xT[nl*40 + rch*8];
    short8 aT0 = *(const short8*)&Tfb[lr*288 + kc*32 + g*8];
    short8 aT1 = *(const short8*)&Tfb[(16+lr)*288 + kc*32 + g*8];
    acc0 = __builtin_amdgcn_mfma_f32_16x16x32_bf16(aT0, bX, acc0, 0,0,0);
    acc1 = __builtin_amdgcn_mfma_f32_16x16x32_bf16(aT1, bX, acc1, 0,0,0);
  }
  int n = n0 + nl;
  if (n < 8480){
    #pragma unroll
    for (int r = 0; r < 4; ++r){
      int m0 = g*4 + r;
      U32[((size_t)b*26 + m0)*8480 + n] = acc0[r];
      int m1 = 16 + m0;
      if (m1 < 26) U32[((size_t)b*26 + m1)*8480 + n] = acc1[r];
    }
  }
}

// Column DFT + mode mix, one block per (j, b, ws); partial G per ws half
__global__ __launch_bounds__(256) void k_spec(const float* __restrict__ U32,
                                              const float* __restrict__ w1r,
                                              const float* __restrict__ w1i,
                                              const float* __restrict__ w2r,
                                              const float* __restrict__ w2i,
                                              float2* __restrict__ G, int l){
  __shared__ float part[256*25];
  __shared__ float Xs[32*25];
  int j = blockIdx.x;
  int b = blockIdx.y;
  int ws = blockIdx.z;
  int tid = threadIdx.x;
  int wsub = tid >> 5, i = tid & 31;
  int kk   = (j < 12) ? j : (24 - j);
  bool cj  = (j >= 12);
  float xr[12], xi[12];
  #pragma unroll
  for (int k = 0; k < 12; ++k){ xr[k] = 0.f; xi[k] = 0.f; }
  const float* ubr = U32 + ((size_t)(b*26 + 2*kk))*8480;
  for (int w = ws*8 + wsub; w < HP; w += 16){
    int n = w*32 + i;
    float ux = ubr[n];
    float uy = ubr[8480 + n];
    if (cj) uy = -uy;
    float bs, bc; sincosf(-TWO_PI*(float)w/(float)HP, &bs, &bc);
    float pr = 1.f, pi = 0.f;
    #pragma unroll
    for (int k = 0; k < 12; ++k){
      xr[k] = fmaf(ux, pr, fmaf(-uy, pi, xr[k]));
      xi[k] = fmaf(ux, pi, fmaf( uy, pr, xi[k]));
      float npr = pr*bc - pi*bs;
      pi = fmaf(pr, bs, pi*bc);
      pr = npr;
    }
  }
  #pragma unroll
  for (int k = 0; k < 12; ++k){
    part[tid*25 + 2*k]     = xr[k];
    part[tid*25 + 2*k + 1] = xi[k];
  }
  __syncthreads();
  {
    int sg = tid >> 5;
    int ii = tid & 31;
    #pragma unroll
    for (int s0 = 0; s0 < 3; ++s0){
      int s = sg*3 + s0;
      float acc = 0.f;
      #pragma unroll
      for (int wq = 0; wq < 8; ++wq) acc += part[(wq*32 + ii)*25 + s];
      Xs[ii*25 + s] = acc;
    }
  }
  __syncthreads();
  int ky = (j < 12) ? j : (j - 12);
  const float* wr = (j < 12) ? w1r : w2r;
  const float* wi = (j < 12) ? w1i : w2i;
  float2* Gp = G + (size_t)ws*73728;
  for (int p = tid; p < 384; p += 256){
    int o = p / 12, kx = p % 12;
    size_t wbase = (size_t)l*147456 + (size_t)o*144 + (size_t)ky*12 + kx;
    float gr = 0.f, gi = 0.f;
    #pragma unroll 4
    for (int i2 = 0; i2 < 32; ++i2){
      float xvr = Xs[i2*25 + 2*kx];
      float xvi = Xs[i2*25 + 2*kx + 1];
      float a = wr[wbase + (size_t)i2*4608];
      float c = wi[wbase + (size_t)i2*4608];
      gr += xvr*a - xvi*c;
      gi += xvr*c + xvi*a;
    }
    Gp[((size_t)(b*32 + o)*24 + j)*12 + kx] = make_float2(gr, gi);
  }
}

// Inverse row synthesis (sums the 2 G partials); writes A as bf16 [b][h][o][32]
__global__ __launch_bounds__(320) void k_idft_h(const float2* __restrict__ G,
                                                unsigned short* __restrict__ A16){
  __shared__ float2 gs[288];
  int bo = blockIdx.x;
  for (int i = threadIdx.x; i < 288; i += 320){
    float2 g0 = G[(size_t)bo*288 + i];
    float2 g1 = G[73728 + (size_t)bo*288 + i];
    gs[i] = make_float2(g0.x + g1.x, g0.y + g1.y);
  }
  __syncthreads();
  int h = threadIdx.x;
  if (h >= HP) return;
  float ar[12], ai[12];
  #pragma unroll
  for (int k = 0; k < 12; ++k){ ar[k] = 0.f; ai[k] = 0.f; }
  for (int j = 0; j < 24; ++j){
    int ky = (j < 12) ? j : (241 + j);
    int t = (ky*h) % HP;
    float s, c; sincosf(TWO_PI*(float)t/(float)HP, &s, &c);
    #pragma unroll
    for (int k = 0; k < 12; ++k){
      float2 g = gs[j*12 + k];
      ar[k] = fmaf(g.x, c, fmaf(-g.y, s, ar[k]));
      ai[k] = fmaf(g.x, s, fmaf( g.y, c, ai[k]));
    }
  }
  int b = bo >> 5, o = bo & 31;
  unsigned short o16[32];
  #pragma unroll
  for (int k = 0; k < 12; ++k){ o16[2*k] = f2b(ar[k]); o16[2*k+1] = f2b(ai[k]); }
  #pragma unroll
  for (int k = 24; k < 32; ++k) o16[k] = 0;
  uint4* ap = (uint4*)(A16 + (((size_t)(b*HP + h))*32 + o)*32);
  #pragma unroll
  for (int q = 0; q < 4; ++q)
    ap[q] = make_uint4(pk(o16[8*q],o16[8*q+1]), pk(o16[8*q+2],o16[8*q+3]),
                       pk(o16[8*q+4],o16[8*q+5]), pk(o16[8*q+6],o16[8*q+7]));
}

// MFMA final, 4 h-rows/block, fragments straight from global (bf16, L1/L2-hot)
__global__ __launch_bounds__(256) void k_final(const unsigned short* __restrict__ A16,
                                               const unsigned short* __restrict__ Tsyn,
                                               const unsigned short* __restrict__ pwb,
                                               const float* __restrict__ pw_b,
                                               unsigned short* __restrict__ xb, int l){
  __shared__ float buf[4][16*36];
  int tid = threadIdx.x;
  int h0 = blockIdx.x*4, b = blockIdx.y;
  int wid = tid>>6, lane = tid&63, lr = lane&15, g = lane>>4, lk = g*8;
  short8 bP0 = *(const short8*)&pwb[l*1024 + lr*32 + lk];
  short8 bP1 = *(const short8*)&pwb[l*1024 + (16+lr)*32 + lk];
  float bias0 = pw_b[l*32 + lr], bias1 = pw_b[l*32 + 16 + lr];
  float* bw = buf[wid];
  const f32x4 z4 = {0.f,0.f,0.f,0.f};
  for (int m = 0; m < 17; ++m){
    int tt = wid + 4*m;              // 0..67
    int hh = tt/17, wt = tt - hh*17;
    int h = h0 + hh;
    if (h >= HP) continue;
    int w0 = wt*16;
    unsigned short* xrow = xb + (size_t)(b*HP + h)*ROWF;
    const unsigned short* arow = A16 + (size_t)(b*HP + h)*1024;
    short8 aT  = *(const short8*)&Tsyn[(w0+lr)*32 + lk];
    short8 aX  = *(const short8*)&xrow[(size_t)(w0+lr)*32 + lk];
    short8 bA0 = *(const short8*)&arow[lr*32 + lk];
    short8 bA1 = *(const short8*)&arow[(16+lr)*32 + lk];
    f32x4 a0 = __builtin_amdgcn_mfma_f32_16x16x32_bf16(aT, bA0, z4, 0,0,0);
    a0 = __builtin_amdgcn_mfma_f32_16x16x32_bf16(aX, bP0, a0, 0,0,0);
    f32x4 a1 = __builtin_amdgcn_mfma_f32_16x16x32_bf16(aT, bA1, z4, 0,0,0);
    a1 = __builtin_amdgcn_mfma_f32_16x16x32_bf16(aX, bP1, a1, 0,0,0);
    #pragma unroll
    for (int r = 0; r < 4; ++r){
      bw[(g*4+r)*36 + lr]      = a0[r] + bias0;
      bw[(g*4+r)*36 + 16 + lr] = a1[r] + bias1;
    }
    asm volatile("s_waitcnt lgkmcnt(0)" ::: "memory");
    __builtin_amdgcn_sched_barrier(0);
    int row = lane >> 2, c0 = (lane & 3)*8;
    int w = w0 + row;
    f32x4 v0 = *(const f32x4*)&bw[row*36 + c0];
    f32x4 v1 = *(const f32x4*)&bw[row*36 + c0 + 4];
    if (w < HP){
      unsigned short o8[8];
      #pragma unroll
      for (int q = 0; q < 4; ++q){
        float va = v0[q], vb = v1[q];
        if (l < 3){ va = gelu_f(va); vb = gelu_f(vb); }
        o8[q] = f2b(va); o8[4+q] = f2b(vb);
      }
      uint4* dst = (uint4*)&xrow[(size_t)w*32 + c0];
      *dst = make_uint4(pk(o8[0],o8[1]), pk(o8[2],o8[3]),
                        pk(o8[4],o8[5]), pk(o8[6],o8[7]));
    }
  }
}

// MFMA head: fc1 via MFMA (fragments from global bf16), gelu -> LDS P (bf16)
// -> fc2 via MFMA, +x_en, write pred & pred_de. No block-wide syncs.
__global__ __launch_bounds__(256) void k_head(const unsigned short* __restrict__ xb,
                                              const float* __restrict__ xen,
                                              const unsigned short* __restrict__ w1b,
                                              const float* __restrict__ fc1b,
                                              const unsigned short* __restrict__ w2b,
                                              const float* __restrict__ fc2b,
                                              float* __restrict__ out){
  __shared__ unsigned short Pm[4][16*136];
  __shared__ float dl[4][64*4];
  int tid = threadIdx.x;
  int b = blockIdx.x >> 8, h = blockIdx.x & 255;
  int wid = tid>>6, lane = tid&63, lr = lane&15, g = lane>>4, lk = g*8;
  short8 bf1[8], bf2[4];
  float b1l[8];
  #pragma unroll
  for (int nt = 0; nt < 8; ++nt){
    int n = nt*16 + lr;
    bf1[nt] = *(const short8*)&w1b[n*32 + lk];
    b1l[nt] = fc1b[n];
  }
  #pragma unroll
  for (int ks = 0; ks < 4; ++ks)
    bf2[ks] = *(const short8*)&w2b[lr*128 + ks*32 + lk];
  float f2c0 = fc2b[0], f2c1 = fc2b[1], f2c2 = fc2b[2];
  const unsigned short* xrow = xb + (size_t)(b*HP + h)*ROWF;
  unsigned short* P = Pm[wid];
  float* dlw = dl[wid];
  const f32x4 z4 = {0.f,0.f,0.f,0.f};
  #pragma unroll
  for (int m = 0; m < 4; ++m){
    int p0 = (wid*4 + m)*16;
    short8 ax = *(const short8*)&xrow[(size_t)(p0 + lr)*32 + lk];
    f32x4 acc[8];
    #pragma unroll
    for (int nt = 0; nt < 8; ++nt)
      acc[nt] = __builtin_amdgcn_mfma_f32_16x16x32_bf16(ax, bf1[nt], z4, 0,0,0);
    #pragma unroll
    for (int nt = 0; nt < 8; ++nt){
      int n = nt*16 + lr;
      float bias = b1l[nt];
      #pragma unroll
      for (int r = 0; r < 4; ++r)
        P[(g*4 + r)*136 + n] = f2b(gelu_f(acc[nt][r] + bias));
    }
    asm volatile("s_waitcnt lgkmcnt(0)" ::: "memory");
    __builtin_amdgcn_sched_barrier(0);
    f32x4 a2 = z4;
    #pragma unroll
    for (int ks = 0; ks < 4; ++ks){
      short8 ap = *(const short8*)&P[lr*136 + ks*32 + lk];
      a2 = __builtin_amdgcn_mfma_f32_16x16x32_bf16(ap, bf2[ks], a2, 0,0,0);
    }
    if (lr < 3){
      #pragma unroll
      for (int r = 0; r < 4; ++r)
        dl[wid][(m*16 + g*4 + r)*4 + lr] = a2[r];
    }
  }
  asm volatile("s_waitcnt lgkmcnt(0)" ::: "memory");
  __builtin_amdgcn_sched_barrier(0);
  int w = wid*64 + lane;
  float d0 = dlw[lane*4+0] + f2c0;
  float d1 = dlw[lane*4+1] + f2c1;
  float d2 = dlw[lane*4+2] + f2c2;
  size_t be = ((size_t)b*3)*65536 + (h<<8) + w;
  float p0 = d0 + xen[be];
  float p1 = d1 + xen[be + 65536];
  float p2 = d2 + xen[be + 131072];
  out[196608 + be]          = p0;
  out[196608 + be + 65536]  = p1;
  out[196608 + be + 131072] = p2;
  if (((h|w)&3) == 0){
    size_t db = ((size_t)b*3)*4096 + ((h>>2)<<6) + (w>>2);
    out[db]        = p0;
    out[db + 4096] = p1;
    out[db + 8192] = p2;
  }
}

extern "C" void kernel_launch(void* const* d_in, const int* in_sizes, int n_in,
                              void* d_out, int out_size, void* d_ws, size_t ws_size,
                              hipStream_t stream){
  const float* x_en  = (const float*)d_in[0];
  const float* fc0_w = (const float*)d_in[2];
  const float* fc0_b = (const float*)d_in[3];
  const float* w1r   = (const float*)d_in[4];
  const float* w1i   = (const float*)d_in[5];
  const float* w2r   = (const float*)d_in[6];
  const float* w2i   = (const float*)d_in[7];
  const float* pw_w  = (const float*)d_in[8];
  const float* pw_b  = (const float*)d_in[9];
  const float* fc1_w = (const float*)d_in[10];
  const float* fc1_b = (const float*)d_in[11];
  const float* fc2_w = (const float*)d_in[12];
  const float* fc2_b = (const float*)d_in[13];
  float* out = (float*)d_out;
  float* ws  = (float*)d_ws;

  unsigned short* xb  = (unsigned short*)(ws + OFF_X);
  float*  U32         = ws + OFF_U;
  float2* G           = (float2*)(ws + OFF_G);
  unsigned short* A16 = (unsigned short*)(ws + OFF_A);
  unsigned short* Tfb = (unsigned short*)(ws + OFF_TFB);
  unsigned short* Ts  = (unsigned short*)(ws + OFF_TS);
  unsigned short* w1b = (unsigned short*)(ws + OFF_W1B);
  unsigned short* w2b = (unsigned short*)(ws + OFF_W2B);
  unsigned short* pwb = (unsigned short*)(ws + OFF_PWB);

  k_init<<<36, 256, 0, stream>>>(Tfb, Ts, w1b, w2b, pwb, fc1_w, fc2_w, pw_w);
  k_fc0<<<2195, 256, 0, stream>>>(x_en, fc0_w, fc0_b, xb, out);
  for (int l = 0; l < 4; ++l){
    k_dftm<<<dim3(133,8), 256, 0, stream>>>(xb, Tfb, U32);
    k_spec<<<dim3(24,8,2), 256, 0, stream>>>(U32, w1r, w1i, w2r, w2i, G, l);
    k_idft_h<<<256, 320, 0, stream>>>(G, A16);
    k_final<<<dim3(67,8), 256, 0, stream>>>(A16, Ts, pwb, pw_b, xb, l);
  }
  k_head<<<2048, 256, 0, stream>>>(xb, x_en, w1b, fc1_b, w2b, fc2_b, out);
}

// Round 9
// 322.456 us; speedup vs baseline: 1.3952x; 1.0985x over previous
//
#include <hip/hip_runtime.h>
#include <math.h>

#define HP 265
#define NPIX 70225        // 265*265
#define ROWF 8480         // HP*32 elements per (b,h) row, channels-last
#define TWO_PI 6.28318530717958647692f

// ws layout (float offsets); xb/A16/weights/twiddle-mats are bf16 (ushort)
#define OFF_X     0            // [8][265][265][32] ushort  = 8,988,800 slots
#define OFF_U     8988800      // [8][26][8480] f32         = 1,763,840
#define OFF_G     10752640     // [2][8][32][24][12] cplx   =   294,912
#define OFF_A     11047552     // [8][265][32][32] ushort   = 1,085,440 slots
#define OFF_TFB   12132992     // [32][288] ushort          =     4,608 slots
#define OFF_TS    12137600     // [272][32] ushort          =     4,352 slots
#define OFF_W1B   12141952     // [128][32] ushort          =     2,048 slots
#define OFF_W2B   12144000     // [16][128] ushort          =     1,024 slots
#define OFF_PWB   12145024     // [4][32][32] ushort        =     2,048 slots

typedef __attribute__((ext_vector_type(8))) short short8;
typedef __attribute__((ext_vector_type(4))) float f32x4;

// tanh-form GELU: x*sigmoid(1.59577x + 0.071355x^3); max |diff vs erf-gelu| ~3e-4
// exp2-folded: 5 VALU + 2 trans ops
__device__ __forceinline__ float gelu_f(float v){
  float x2 = v*v;
  float p  = fmaf(x2, 0.10295597f, 2.30212056f);   // (1.59577+0.0713548x^2)*log2e
  float tn = -v*p;
  float e  = __builtin_amdgcn_exp2f(tn);
  float r  = __builtin_amdgcn_rcpf(1.0f + e);
  return v * r;
}
__device__ __forceinline__ unsigned short f2b(float f){
  unsigned u = __float_as_uint(f);
  u += 0x7FFFu + ((u >> 16) & 1u);
  return (unsigned short)(u >> 16);
}
__device__ __forceinline__ unsigned pk(unsigned short lo, unsigned short hi){
  return (unsigned)lo | ((unsigned)hi << 16);
}

// Twiddle mats + bf16 weight pre-conversion (tiny, once per call)
__global__ void k_init(unsigned short* __restrict__ Tfb, unsigned short* __restrict__ Ts,
                       unsigned short* __restrict__ w1b, unsigned short* __restrict__ w2b,
                       unsigned short* __restrict__ pwb,
                       const float* __restrict__ fc1w, const float* __restrict__ fc2w,
                       const float* __restrict__ pw_w){
  int idx = blockIdx.x*256 + threadIdx.x;
  if (idx < 32*288){                    // analysis twiddles: row 2k=cos, 2k+1=-sin
    int m = idx / 288, hc = idx % 288;
    unsigned short v = 0;
    if (m < 26 && hc < 265){
      int k = m >> 1;
      int t = (hc*k) % HP;
      float s, c; sincosf(TWO_PI*(float)t/(float)HP, &s, &c);
      v = f2b((m & 1) ? -s : c);
    }
    Tfb[idx] = v;
  }
  if (idx < 272*32){                    // synthesis twiddles (invN folded)
    int w = idx >> 5, kap = idx & 31;
    unsigned short v = 0;
    if (w < HP && kap < 24){
      int k = kap >> 1;
      int t = (w*k) % HP;
      float s, c; sincosf(TWO_PI*(float)t/(float)HP, &s, &c);
      const float invN = 1.f/70225.f;
      float val = (!(kap&1)) ? invN*(k==0 ? 1.f : 2.f*c)
                             : ((k==0) ? 0.f : -invN*2.f*s);
      v = f2b(val);
    }
    Ts[idx] = v;
  }
  if (idx < 4096){                      // w1b[n*32+k] = fc1w[k*128+n]
    int n = idx >> 5, k = idx & 31;
    w1b[idx] = f2b(fc1w[k*128 + n]);
  }
  if (idx < 2048){                      // w2b[n*128+k] = fc2w[k*3+n], n<3 else 0
    int n = idx >> 7, k = idx & 127;
    w2b[idx] = (n < 3) ? f2b(fc2w[k*3 + n]) : (unsigned short)0;
  }
  if (idx < 4096)                       // pwb = pw_w bf16 (same [l][o][i] layout)
    pwb[idx] = f2b(pw_w[idx]);
}

// fc0 (3->32, bf16 channels-last, zero pad) + copy x_en/x_de to out
__global__ __launch_bounds__(256) void k_fc0(const float* __restrict__ xen,
                                             const float* __restrict__ w0,
                                             const float* __restrict__ b0,
                                             unsigned short* __restrict__ xb,
                                             float* __restrict__ out){
  int idx = blockIdx.x*256 + threadIdx.x;
  if (idx >= 8*NPIX) return;
  int w = idx % HP; int t = idx / HP; int h = t % HP; int b = t / HP;
  unsigned short o16[32];
  if (h < 256 && w < 256){
    const float* xp = xen + (((size_t)b*3)*256 + h)*256 + w;
    float c0 = xp[0], c1 = xp[65536], c2 = xp[131072];
    #pragma unroll
    for (int d = 0; d < 32; ++d)
      o16[d] = f2b(b0[d] + c0*w0[d] + c1*w0[32+d] + c2*w0[64+d]);
    size_t be = ((size_t)b*3)*65536 + (h<<8) + w;
    out[1769472 + be]          = c0;
    out[1769472 + be + 65536]  = c1;
    out[1769472 + be + 131072] = c2;
    if (((h|w)&3) == 0){
      size_t db = ((size_t)b*3)*4096 + ((h>>2)<<6) + (w>>2);
      out[98304 + db]        = c0;
      out[98304 + db + 4096] = c1;
      out[98304 + db + 8192] = c2;
    }
  } else {
    #pragma unroll
    for (int d = 0; d < 32; ++d) o16[d] = 0;
  }
  uint4* dst = (uint4*)(xb + (size_t)idx*32);
  #pragma unroll
  for (int q = 0; q < 4; ++q)
    dst[q] = make_uint4(pk(o16[8*q],o16[8*q+1]), pk(o16[8*q+2],o16[8*q+3]),
                        pk(o16[8*q+4],o16[8*q+5]), pk(o16[8*q+6],o16[8*q+7]));
}

// MFMA h-DFT, LDS-free: U[b][m<26][n] = sum_h Tfb[m][h] * x[b][h][n].
// B-fragment (col n, k-run of 8 h) loaded DIRECTLY as 8 strided u16 — the
// same global accesses the old LDS staging made, minus the round trip.
__global__ __launch_bounds__(256) void k_dftm(const unsigned short* __restrict__ xb,
                                              const unsigned short* __restrict__ Tfb,
                                              float* __restrict__ U32){
  int tid = threadIdx.x;
  int wv = tid>>6, lane = tid&63, lr = lane&15, g = lane>>4, lk = g*8;
  int n0 = blockIdx.x*64;
  int b  = blockIdx.y;
  int n  = n0 + wv*16 + lr;
  const unsigned short* xcol = xb + (size_t)b*HP*ROWF + n;
  f32x4 acc0 = {0.f,0.f,0.f,0.f}, acc1 = {0.f,0.f,0.f,0.f};
  #pragma unroll
  for (int kc = 0; kc < 9; ++kc){
    short8 hv;
    int hb = kc*32 + lk;
    #pragma unroll
    for (int q = 0; q < 8; ++q){
      int h = hb + q;
      hv[q] = (h < HP) ? (short)xcol[(size_t)h*ROWF] : (short)0;
    }
    short8 aT0 = *(const short8*)&Tfb[lr*288 + kc*32 + lk];
    short8 aT1 = *(const short8*)&Tfb[(16+lr)*288 + kc*32 + lk];
    acc0 = __builtin_amdgcn_mfma_f32_16x16x32_bf16(aT0, hv, acc0, 0,0,0);
    acc1 = __builtin_amdgcn_mfma_f32_16x16x32_bf16(aT1, hv, acc1, 0,0,0);
  }
  if (n < 8480){
    #pragma unroll
    for (int r = 0; r < 4; ++r){
      int m0 = g*4 + r;
      U32[((size_t)b*26 + m0)*8480 + n] = acc0[r];
      int m1 = 16 + m0;
      if (m1 < 26) U32[((size_t)b*26 + m1)*8480 + n] = acc1[r];
    }
  }
}

// Column DFT + mode mix, one block per (j, b, ws); partial G per ws half
__global__ __launch_bounds__(256) void k_spec(const float* __restrict__ U32,
                                              const float* __restrict__ w1r,
                                              const float* __restrict__ w1i,
                                              const float* __restrict__ w2r,
                                              const float* __restrict__ w2i,
                                              float2* __restrict__ G, int l){
  __shared__ float part[256*25];
  __shared__ float Xs[32*25];
  int j = blockIdx.x;
  int b = blockIdx.y;
  int ws = blockIdx.z;
  int tid = threadIdx.x;
  int wsub = tid >> 5, i = tid & 31;
  int kk   = (j < 12) ? j : (24 - j);
  bool cj  = (j >= 12);
  float xr[12], xi[12];
  #pragma unroll
  for (int k = 0; k < 12; ++k){ xr[k] = 0.f; xi[k] = 0.f; }
  const float* ubr = U32 + ((size_t)(b*26 + 2*kk))*8480;
  for (int w = ws*8 + wsub; w < HP; w += 16){
    int n = w*32 + i;
    float ux = ubr[n];
    float uy = ubr[8480 + n];
    if (cj) uy = -uy;
    float bs, bc; sincosf(-TWO_PI*(float)w/(float)HP, &bs, &bc);
    float pr = 1.f, pi = 0.f;
    #pragma unroll
    for (int k = 0; k < 12; ++k){
      xr[k] = fmaf(ux, pr, fmaf(-uy, pi, xr[k]));
      xi[k] = fmaf(ux, pi, fmaf( uy, pr, xi[k]));
      float npr = pr*bc - pi*bs;
      pi = fmaf(pr, bs, pi*bc);
      pr = npr;
    }
  }
  #pragma unroll
  for (int k = 0; k < 12; ++k){
    part[tid*25 + 2*k]     = xr[k];
    part[tid*25 + 2*k + 1] = xi[k];
  }
  __syncthreads();
  {
    int sg = tid >> 5;
    int ii = tid & 31;
    #pragma unroll
    for (int s0 = 0; s0 < 3; ++s0){
      int s = sg*3 + s0;
      float acc = 0.f;
      #pragma unroll
      for (int wq = 0; wq < 8; ++wq) acc += part[(wq*32 + ii)*25 + s];
      Xs[ii*25 + s] = acc;
    }
  }
  __syncthreads();
  int ky = (j < 12) ? j : (j - 12);
  const float* wr = (j < 12) ? w1r : w2r;
  const float* wi = (j < 12) ? w1i : w2i;
  float2* Gp = G + (size_t)ws*73728;
  for (int p = tid; p < 384; p += 256){
    int o = p / 12, kx = p % 12;
    size_t wbase = (size_t)l*147456 + (size_t)o*144 + (size_t)ky*12 + kx;
    float gr = 0.f, gi = 0.f;
    #pragma unroll 4
    for (int i2 = 0; i2 < 32; ++i2){
      float xvr = Xs[i2*25 + 2*kx];
      float xvi = Xs[i2*25 + 2*kx + 1];
      float a = wr[wbase + (size_t)i2*4608];
      float c = wi[wbase + (size_t)i2*4608];
      gr += xvr*a - xvi*c;
      gi += xvr*c + xvi*a;
    }
    Gp[((size_t)(b*32 + o)*24 + j)*12 + kx] = make_float2(gr, gi);
  }
}

// Inverse row synthesis (sums the 2 G partials); writes A as bf16 [b][h][o][32]
__global__ __launch_bounds__(320) void k_idft_h(const float2* __restrict__ G,
                                                unsigned short* __restrict__ A16){
  __shared__ float2 gs[288];
  int bo = blockIdx.x;
  for (int i = threadIdx.x; i < 288; i += 320){
    float2 g0 = G[(size_t)bo*288 + i];
    float2 g1 = G[73728 + (size_t)bo*288 + i];
    gs[i] = make_float2(g0.x + g1.x, g0.y + g1.y);
  }
  __syncthreads();
  int h = threadIdx.x;
  if (h >= HP) return;
  float ar[12], ai[12];
  #pragma unroll
  for (int k = 0; k < 12; ++k){ ar[k] = 0.f; ai[k] = 0.f; }
  for (int j = 0; j < 24; ++j){
    int ky = (j < 12) ? j : (241 + j);
    int t = (ky*h) % HP;
    float s, c; sincosf(TWO_PI*(float)t/(float)HP, &s, &c);
    #pragma unroll
    for (int k = 0; k < 12; ++k){
      float2 g = gs[j*12 + k];
      ar[k] = fmaf(g.x, c, fmaf(-g.y, s, ar[k]));
      ai[k] = fmaf(g.x, s, fmaf( g.y, c, ai[k]));
    }
  }
  int b = bo >> 5, o = bo & 31;
  unsigned short o16[32];
  #pragma unroll
  for (int k = 0; k < 12; ++k){ o16[2*k] = f2b(ar[k]); o16[2*k+1] = f2b(ai[k]); }
  #pragma unroll
  for (int k = 24; k < 32; ++k) o16[k] = 0;
  uint4* ap = (uint4*)(A16 + (((size_t)(b*HP + h))*32 + o)*32);
  #pragma unroll
  for (int q = 0; q < 4; ++q)
    ap[q] = make_uint4(pk(o16[8*q],o16[8*q+1]), pk(o16[8*q+2],o16[8*q+3]),
                       pk(o16[8*q+4],o16[8*q+5]), pk(o16[8*q+6],o16[8*q+7]));
}

// MFMA final, operand-swapped (D[o][w]): each lane holds 8 adjacent channels
// of its pixel -> pack + store from registers. No LDS, no in-loop waits.
// One wave per h-row (4 rows/block).
__global__ __launch_bounds__(256) void k_final(const unsigned short* __restrict__ A16,
                                               const unsigned short* __restrict__ Tsyn,
                                               const unsigned short* __restrict__ pwb,
                                               const float* __restrict__ pw_b,
                                               unsigned short* __restrict__ xb, int l){
  int tid = threadIdx.x;
  int wv = tid>>6, lane = tid&63, lr = lane&15, g = lane>>4, lk = g*8;
  int h = blockIdx.x*4 + wv;
  int b = blockIdx.y;
  if (h >= HP) return;
  const unsigned short* arow = A16 + (size_t)(b*HP + h)*1024;
  short8 aA0 = *(const short8*)&arow[lr*32 + lk];          // A: rows o=0..15
  short8 aA1 = *(const short8*)&arow[(16+lr)*32 + lk];     //    rows o=16..31
  short8 aP0 = *(const short8*)&pwb[l*1024 + lr*32 + lk];
  short8 aP1 = *(const short8*)&pwb[l*1024 + (16+lr)*32 + lk];
  float4 vb0 = *(const float4*)&pw_b[l*32 + g*4];
  float4 vb1 = *(const float4*)&pw_b[l*32 + 16 + g*4];
  unsigned short* xrow = xb + (size_t)(b*HP + h)*ROWF;
  const f32x4 z4 = {0.f,0.f,0.f,0.f};
  for (int wt = 0; wt < 17; ++wt){
    int w = wt*16 + lr;
    short8 bT = *(const short8*)&Tsyn[(size_t)w*32 + lk];  // B: col w
    short8 bX = *(const short8*)&xrow[(size_t)w*32 + lk];
    f32x4 a0 = __builtin_amdgcn_mfma_f32_16x16x32_bf16(aA0, bT, z4, 0,0,0);
    a0 = __builtin_amdgcn_mfma_f32_16x16x32_bf16(aP0, bX, a0, 0,0,0);
    f32x4 a1 = __builtin_amdgcn_mfma_f32_16x16x32_bf16(aA1, bT, z4, 0,0,0);
    a1 = __builtin_amdgcn_mfma_f32_16x16x32_bf16(aP1, bX, a1, 0,0,0);
    if (w < HP){
      float v0[4], v1[4];
      v0[0]=a0[0]+vb0.x; v0[1]=a0[1]+vb0.y; v0[2]=a0[2]+vb0.z; v0[3]=a0[3]+vb0.w;
      v1[0]=a1[0]+vb1.x; v1[1]=a1[1]+vb1.y; v1[2]=a1[2]+vb1.z; v1[3]=a1[3]+vb1.w;
      if (l < 3){
        #pragma unroll
        for (int r = 0; r < 4; ++r){ v0[r] = gelu_f(v0[r]); v1[r] = gelu_f(v1[r]); }
      }
      *(uint2*)&xrow[(size_t)w*32 + g*4] =
          make_uint2(pk(f2b(v0[0]),f2b(v0[1])), pk(f2b(v0[2]),f2b(v0[3])));
      *(uint2*)&xrow[(size_t)w*32 + 16 + g*4] =
          make_uint2(pk(f2b(v1[0]),f2b(v1[1])), pk(f2b(v1[2]),f2b(v1[3])));
    }
  }
}

// MFMA head, fc1 operand-swapped (D[n][pix]): P^T written as b64 pairs
// (conflict-light), fc2 unchanged orientation, direct register epilogue.
__global__ __launch_bounds__(256) void k_head(const unsigned short* __restrict__ xb,
                                              const float* __restrict__ xen,
                                              const unsigned short* __restrict__ w1b,
                                              const float* __restrict__ fc1b,
                                              const unsigned short* __restrict__ w2b,
                                              const float* __restrict__ fc2b,
                                              float* __restrict__ out){
  __shared__ unsigned short Pm[4][16*136];
  int tid = threadIdx.x;
  int b = blockIdx.x >> 8, h = blockIdx.x & 255;
  int wv = tid>>6, lane = tid&63, lr = lane&15, g = lane>>4, lk = g*8;
  short8 bf1[8], bf2[4];
  #pragma unroll
  for (int nt = 0; nt < 8; ++nt)
    bf1[nt] = *(const short8*)&w1b[(nt*16+lr)*32 + lk];    // A-frag rows n1
  #pragma unroll
  for (int ks = 0; ks < 4; ++ks)
    bf2[ks] = *(const short8*)&w2b[lr*128 + ks*32 + lk];   // B-frag col c=lr
  float f2c = (lr < 3) ? fc2b[lr] : 0.f;
  const unsigned short* xrow = xb + (size_t)(b*HP + h)*ROWF;
  unsigned short* P = Pm[wv];
  const f32x4 z4 = {0.f,0.f,0.f,0.f};
  #pragma unroll
  for (int m = 0; m < 4; ++m){
    int p0 = (wv*4 + m)*16;
    short8 ax = *(const short8*)&xrow[(size_t)(p0 + lr)*32 + lk];  // B: col pix
    f32x4 acc[8];
    #pragma unroll
    for (int nt = 0; nt < 8; ++nt)
      acc[nt] = __builtin_amdgcn_mfma_f32_16x16x32_bf16(bf1[nt], ax, z4, 0,0,0);
    #pragma unroll
    for (int nt = 0; nt < 8; ++nt){
      float4 bb = *(const float4*)&fc1b[nt*16 + g*4];      // L1-hot broadcast
      float h0 = gelu_f(acc[nt][0] + bb.x);
      float h1 = gelu_f(acc[nt][1] + bb.y);
      float h2 = gelu_f(acc[nt][2] + bb.z);
      float h3 = gelu_f(acc[nt][3] + bb.w);
      *(uint2*)&P[lr*136 + nt*16 + g*4] =
          make_uint2(pk(f2b(h0),f2b(h1)), pk(f2b(h2),f2b(h3)));
    }
    asm volatile("s_waitcnt lgkmcnt(0)" ::: "memory");
    __builtin_amdgcn_sched_barrier(0);
    f32x4 a2 = z4;
    #pragma unroll
    for (int ks = 0; ks < 4; ++ks){
      short8 ap = *(const short8*)&P[lr*136 + ks*32 + lk]; // A: row pix=lr
      a2 = __builtin_amdgcn_mfma_f32_16x16x32_bf16(ap, bf2[ks], a2, 0,0,0);
    }
    // D2[pix][c]: lane (g,lr<3): pixels p0+g*4+r, channel lr
    if (lr < 3){
      size_t base = ((size_t)(b*3 + lr))*65536 + (h<<8) + p0 + g*4;
      float4 xe = *(const float4*)&xen[base];
      float4 pr;
      pr.x = a2[0] + f2c + xe.x;
      pr.y = a2[1] + f2c + xe.y;
      pr.z = a2[2] + f2c + xe.z;
      pr.w = a2[3] + f2c + xe.w;
      *(float4*)&out[196608 + base] = pr;
      if ((h & 3) == 0){
        int w4 = (p0 + g*4) >> 2;
        out[((size_t)(b*3 + lr))*4096 + ((h>>2)<<6) + w4] = pr.x;
      }
    }
  }
}

extern "C" void kernel_launch(void* const* d_in, const int* in_sizes, int n_in,
                              void* d_out, int out_size, void* d_ws, size_t ws_size,
                              hipStream_t stream){
  const float* x_en  = (const float*)d_in[0];
  const float* fc0_w = (const float*)d_in[2];
  const float* fc0_b = (const float*)d_in[3];
  const float* w1r   = (const float*)d_in[4];
  const float* w1i   = (const float*)d_in[5];
  const float* w2r   = (const float*)d_in[6];
  const float* w2i   = (const float*)d_in[7];
  const float* pw_w  = (const float*)d_in[8];
  const float* pw_b  = (const float*)d_in[9];
  const float* fc1_w = (const float*)d_in[10];
  const float* fc1_b = (const float*)d_in[11];
  const float* fc2_w = (const float*)d_in[12];
  const float* fc2_b = (const float*)d_in[13];
  float* out = (float*)d_out;
  float* ws  = (float*)d_ws;

  unsigned short* xb  = (unsigned short*)(ws + OFF_X);
  float*  U32         = ws + OFF_U;
  float2* G           = (float2*)(ws + OFF_G);
  unsigned short* A16 = (unsigned short*)(ws + OFF_A);
  unsigned short* Tfb = (unsigned short*)(ws + OFF_TFB);
  unsigned short* Ts  = (unsigned short*)(ws + OFF_TS);
  unsigned short* w1b = (unsigned short*)(ws + OFF_W1B);
  unsigned short* w2b = (unsigned short*)(ws + OFF_W2B);
  unsigned short* pwb = (unsigned short*)(ws + OFF_PWB);

  k_init<<<36, 256, 0, stream>>>(Tfb, Ts, w1b, w2b, pwb, fc1_w, fc2_w, pw_w);
  k_fc0<<<2195, 256, 0, stream>>>(x_en, fc0_w, fc0_b, xb, out);
  for (int l = 0; l < 4; ++l){
    k_dftm<<<dim3(133,8), 256, 0, stream>>>(xb, Tfb, U32);
    k_spec<<<dim3(24,8,2), 256, 0, stream>>>(U32, w1r, w1i, w2r, w2i, G, l);
    k_idft_h<<<256, 320, 0, stream>>>(G, A16);
    k_final<<<dim3(67,8), 256, 0, stream>>>(A16, Ts, pwb, pw_b, xb, l);
  }
  k_head<<<2048, 256, 0, stream>>>(xb, x_en, w1b, fc1_b, w2b, fc2_b, out);
}